// Round 4
// baseline (572.883 us; speedup 1.0000x reference)
//
#include <hip/hip_runtime.h>
#include <hip/hip_bf16.h>

#define SEQ   512
#define BATCH 1024
#define HD    64
#define TCH   64    // x-chunk length (steps); 8 KB bf16 per chunk

typedef __attribute__((ext_vector_type(8))) short bf16x8;   // 8 bf16 = 4 VGPR
typedef __attribute__((ext_vector_type(4))) float f32x4;    // MFMA acc

// float -> bf16 raw bits, round-to-nearest-even
__device__ __forceinline__ unsigned short f2bf(float f) {
    unsigned u = __float_as_uint(f);
    return (unsigned short)((u + 0x7FFFu + ((u >> 16) & 1u)) >> 16);
}

// Persistent LSTM, 1 sample per block (1024 blocks -> 4 blocks/CU).
// Wave w owns hidden units [16w,16w+16); its N-tiles {w,4+w,8+w,12+w} are the
// i/f/g/o slices for those units. A-row 0 is the sample; rows 1..15 broadcast
// the same LDS address (free) and produce ignored D rows. Cell update happens
// on lanes 0..15 directly from acc[g][0] -- no shuffles, one barrier/step.
__global__ __launch_bounds__(256, 4)
void lstm_bcast(const float* __restrict__ x,
                const float* __restrict__ W_ih,
                const float* __restrict__ W_hh,
                const float* __restrict__ b_ih,
                const float* __restrict__ b_hh,
                float* __restrict__ out)
{
    __shared__ __align__(16) unsigned short xch[TCH * HD];  // 8 KB: [t][k] bf16
    __shared__ __align__(16) unsigned short hb[2][HD];      // ping-pong h (bf16)

    const int tid = threadIdx.x;
    const int w   = tid >> 6;        // wave 0..3
    const int ln  = tid & 63;
    const int col = ln & 15;         // MFMA column / owned unit within wave
    const int kg  = ln >> 4;         // k-group of A/B fragments
    const int s   = blockIdx.x;      // batch sample

    // ---- one-time: B fragments global fp32 -> bf16 registers ----
    // B[k][n] = W[n][k]; lane holds 8 consecutive k of gate n = ntile*16+col.
    bf16x8 bfr[4][4];                // [gate i/f/g/o][k-tile]
    #pragma unroll
    for (int g4 = 0; g4 < 4; ++g4) {
        #pragma unroll
        for (int kt = 0; kt < 4; ++kt) {
            const int n = (g4 * 4 + w) * 16 + col;
            const int k = kt * 32 + kg * 8;
            const float* src = (k < 64) ? (W_ih + n * 64 + k)
                                        : (W_hh + n * 64 + (k - 64));
            const float4 lo = *(const float4*)src;
            const float4 hi = *(const float4*)(src + 4);
            bf16x8 v;
            v[0] = (short)f2bf(lo.x); v[1] = (short)f2bf(lo.y);
            v[2] = (short)f2bf(lo.z); v[3] = (short)f2bf(lo.w);
            v[4] = (short)f2bf(hi.x); v[5] = (short)f2bf(hi.y);
            v[6] = (short)f2bf(hi.z); v[7] = (short)f2bf(hi.w);
            bfr[g4][kt] = v;
        }
    }
    float bias[4];
    #pragma unroll
    for (int g4 = 0; g4 < 4; ++g4) {
        const int gg = g4 * 64 + w * 16 + col;
        bias[g4] = b_ih[gg] + b_hh[gg];
    }

    if (tid < 2 * HD) hb[tid >> 6][tid & 63] = 0;   // h0 = 0 (both buffers)

    // ---- chunk 0 of x -> LDS (bf16) ----
    #pragma unroll 4
    for (int j = 0; j < (TCH * HD) / 256; ++j) {
        const int idx = tid + j * 256;
        const int tt = idx >> 6, k = idx & 63;
        xch[idx] = f2bf(x[((size_t)tt * BATCH + s) * HD + k]);
    }
    __syncthreads();

    float c_st = 0.f;                 // cell state (lanes 0..15: unit w*16+col)
    const f32x4 z4 = {0.f, 0.f, 0.f, 0.f};   // persistent zero C operand
    int p = 0;
    float* outp = out + (size_t)s * HD + w * 16 + col;

    for (int t = 0; t < SEQ; ++t) {
        const int tc = t & (TCH - 1);
        // A fragments: broadcast reads (all rows same address -> conflict-free)
        const bf16x8 ax0 = *(const bf16x8*)&xch[tc * HD + kg * 8];       // k 0..31
        const bf16x8 ax1 = *(const bf16x8*)&xch[tc * HD + 32 + kg * 8];  // k 32..63
        const bf16x8 ah0 = *(const bf16x8*)&hb[p][kg * 8];               // k 64..95
        const bf16x8 ah1 = *(const bf16x8*)&hb[p][32 + kg * 8];          // k 96..127

        f32x4 acc[4];
        #pragma unroll
        for (int g4 = 0; g4 < 4; ++g4) {
            f32x4 a = __builtin_amdgcn_mfma_f32_16x16x32_bf16(ax0, bfr[g4][0], z4, 0, 0, 0);
            a = __builtin_amdgcn_mfma_f32_16x16x32_bf16(ax1, bfr[g4][1], a, 0, 0, 0);
            a = __builtin_amdgcn_mfma_f32_16x16x32_bf16(ah0, bfr[g4][2], a, 0, 0, 0);
            a = __builtin_amdgcn_mfma_f32_16x16x32_bf16(ah1, bfr[g4][3], a, 0, 0, 0);
            acc[g4] = a;
        }

        // ---- cell update: D row 0 = lanes 0..15, reg 0. No cross-lane ops.
        if (ln < 16) {
            const float giv = acc[0][0] + bias[0];
            const float gfv = acc[1][0] + bias[1];
            const float ggv = acc[2][0] + bias[2];
            const float gov = acc[3][0] + bias[3];
            const float iv = 1.f / (1.f + __expf(-giv));
            const float fv = 1.f / (1.f + __expf(-gfv));
            const float gv = 1.f - 2.f / (__expf(2.f * ggv) + 1.f);   // tanh
            const float ov = 1.f / (1.f + __expf(-gov));
            c_st = fv * c_st + iv * gv;
            const float th = 1.f - 2.f / (__expf(2.f * c_st) + 1.f);  // tanh
            const float h  = ov * th;
            outp[(size_t)t * (BATCH * HD)] = h;
            hb[p ^ 1][w * 16 + col] = f2bf(h);
        }
        p ^= 1;

        // ---- chunk refill every TCH steps ----
        if (tc == TCH - 1 && t + 1 < SEQ) {
            __syncthreads();          // all waves done reading old chunk
            const int t0 = t + 1;
            #pragma unroll 4
            for (int j = 0; j < (TCH * HD) / 256; ++j) {
                const int idx = tid + j * 256;
                const int tt = idx >> 6, k = idx & 63;
                xch[idx] = f2bf(x[((size_t)(t0 + tt) * BATCH + s) * HD + k]);
            }
        }
        __syncthreads();              // h (and new chunk) visible for t+1
    }
}

extern "C" void kernel_launch(void* const* d_in, const int* in_sizes, int n_in,
                              void* d_out, int out_size, void* d_ws, size_t ws_size,
                              hipStream_t stream) {
    const float* x    = (const float*)d_in[0];
    const float* W_ih = (const float*)d_in[1];
    const float* W_hh = (const float*)d_in[2];
    const float* b_ih = (const float*)d_in[3];
    const float* b_hh = (const float*)d_in[4];
    float* out = (float*)d_out;

    lstm_bcast<<<BATCH, 256, 0, stream>>>(x, W_ih, W_hh, b_ih, b_hh, out);
}

// Round 5
// 321.266 us; speedup vs baseline: 1.7832x; 1.7832x over previous
//
#include <hip/hip_runtime.h>
#include <hip/hip_bf16.h>

#define SEQ   512
#define BATCH 1024
#define HD    64
#define NS    2      // samples per block -> 512 blocks (2 blocks/CU)
#define TCH   64     // x-chunk steps staged in LDS (16 KB)

typedef __attribute__((ext_vector_type(8))) short bf16x8;   // 8 bf16 = 4 VGPR
typedef __attribute__((ext_vector_type(4))) float f32x4;    // MFMA acc

// float -> bf16 raw bits, round-to-nearest-even
__device__ __forceinline__ unsigned short f2bf(float f) {
    unsigned u = __float_as_uint(f);
    return (unsigned short)((u + 0x7FFFu + ((u >> 16) & 1u)) >> 16);
}

// Persistent LSTM, 2 samples/block, 512 blocks (2/CU for latency overlap).
// Wave w owns hidden units [16w,16w+16); N-tiles {w,4+w,8+w,12+w} = i/f/g/o.
// Samples mapped to A-rows {0,4} (row parity (ln>>2)&1) so D puts sample 0 on
// lanes 0-15 reg0 and sample 1 on lanes 16-31 reg0: cell update is 32 lanes
// wide with NO cross-lane ops. Bias rides the MFMA C operand. One barrier/step.
__global__ __launch_bounds__(256, 2)
void lstm_v3(const float* __restrict__ x,
             const float* __restrict__ W_ih,
             const float* __restrict__ W_hh,
             const float* __restrict__ b_ih,
             const float* __restrict__ b_hh,
             float* __restrict__ out)
{
    __shared__ __align__(16) unsigned short xch[TCH][NS][HD]; // 16 KB bf16
    __shared__ __align__(16) unsigned short hb[2][NS][HD];    // 512 B ping-pong

    const int tid = threadIdx.x;
    const int w   = tid >> 6;        // wave 0..3
    const int ln  = tid & 63;
    const int col = ln & 15;         // MFMA column / unit within wave
    const int kg  = ln >> 4;         // k-group of A/B fragments
    const int sBase = blockIdx.x * NS;

    // ---- one-time: B fragments global fp32 -> bf16 registers ----
    bf16x8 bfr[4][4];                // [gate][k-tile]
    #pragma unroll
    for (int g4 = 0; g4 < 4; ++g4) {
        #pragma unroll
        for (int kt = 0; kt < 4; ++kt) {
            const int n = (g4 * 4 + w) * 16 + col;
            const int k = kt * 32 + kg * 8;
            const float* src = (k < 64) ? (W_ih + n * 64 + k)
                                        : (W_hh + n * 64 + (k - 64));
            const float4 lo = *(const float4*)src;
            const float4 hi = *(const float4*)(src + 4);
            bf16x8 v;
            v[0] = (short)f2bf(lo.x); v[1] = (short)f2bf(lo.y);
            v[2] = (short)f2bf(lo.z); v[3] = (short)f2bf(lo.w);
            v[4] = (short)f2bf(hi.x); v[5] = (short)f2bf(hi.y);
            v[6] = (short)f2bf(hi.z); v[7] = (short)f2bf(hi.w);
            bfr[g4][kt] = v;
        }
    }
    f32x4 bias4[4];                  // C-operand bias (same for all rows)
    #pragma unroll
    for (int g4 = 0; g4 < 4; ++g4) {
        const int gg = g4 * 64 + w * 16 + col;
        const float b = b_ih[gg] + b_hh[gg];
        bias4[g4][0] = b; bias4[g4][1] = b; bias4[g4][2] = b; bias4[g4][3] = b;
    }

    ((unsigned short*)hb)[tid] = 0;  // 2*NS*64 = 256 shorts: h0 = 0

    const int row2 = (ln >> 2) & 1;  // A-row -> sample slot (rows 0-3:s0, 4-7:s1, ...)
    const int sloc = ln >> 4;        // cell lane -> sample (valid for ln<32)
    const int unit = w * 16 + col;

    float c_st = 0.f;
    int p = 0;
    float* outp = out + (size_t)(sBase + sloc) * HD + unit;

    for (int t0 = 0; t0 < SEQ; t0 += TCH) {
        // ---- refill x chunk (float2 loads, bf16 pack) ----
        #pragma unroll
        for (int j = 0; j < (TCH * NS * HD) / (256 * 2); ++j) {   // 16 iters
            const int idx = tid + j * 256;
            const int tt = idx >> 6, rem = idx & 63;
            const int sl = rem >> 5, k2 = rem & 31;
            const float2 v = *(const float2*)&x[(((size_t)(t0 + tt) * BATCH) + sBase + sl) * HD + k2 * 2];
            const unsigned pk = (unsigned)f2bf(v.x) | ((unsigned)f2bf(v.y) << 16);
            *(unsigned*)&xch[tt][sl][k2 * 2] = pk;
        }
        __syncthreads();

        for (int tc = 0; tc < TCH; ++tc) {
            const int t = t0 + tc;
            const bf16x8 ax0 = *(const bf16x8*)&xch[tc][row2][kg * 8];
            const bf16x8 ax1 = *(const bf16x8*)&xch[tc][row2][32 + kg * 8];
            const bf16x8 ah0 = *(const bf16x8*)&hb[p][row2][kg * 8];
            const bf16x8 ah1 = *(const bf16x8*)&hb[p][row2][32 + kg * 8];

            // k-outer interleave: 4 independent accumulation chains
            f32x4 a0 = __builtin_amdgcn_mfma_f32_16x16x32_bf16(ax0, bfr[0][0], bias4[0], 0, 0, 0);
            f32x4 a1 = __builtin_amdgcn_mfma_f32_16x16x32_bf16(ax0, bfr[1][0], bias4[1], 0, 0, 0);
            f32x4 a2 = __builtin_amdgcn_mfma_f32_16x16x32_bf16(ax0, bfr[2][0], bias4[2], 0, 0, 0);
            f32x4 a3 = __builtin_amdgcn_mfma_f32_16x16x32_bf16(ax0, bfr[3][0], bias4[3], 0, 0, 0);
            a0 = __builtin_amdgcn_mfma_f32_16x16x32_bf16(ax1, bfr[0][1], a0, 0, 0, 0);
            a1 = __builtin_amdgcn_mfma_f32_16x16x32_bf16(ax1, bfr[1][1], a1, 0, 0, 0);
            a2 = __builtin_amdgcn_mfma_f32_16x16x32_bf16(ax1, bfr[2][1], a2, 0, 0, 0);
            a3 = __builtin_amdgcn_mfma_f32_16x16x32_bf16(ax1, bfr[3][1], a3, 0, 0, 0);
            a0 = __builtin_amdgcn_mfma_f32_16x16x32_bf16(ah0, bfr[0][2], a0, 0, 0, 0);
            a1 = __builtin_amdgcn_mfma_f32_16x16x32_bf16(ah0, bfr[1][2], a1, 0, 0, 0);
            a2 = __builtin_amdgcn_mfma_f32_16x16x32_bf16(ah0, bfr[2][2], a2, 0, 0, 0);
            a3 = __builtin_amdgcn_mfma_f32_16x16x32_bf16(ah0, bfr[3][2], a3, 0, 0, 0);
            a0 = __builtin_amdgcn_mfma_f32_16x16x32_bf16(ah1, bfr[0][3], a0, 0, 0, 0);
            a1 = __builtin_amdgcn_mfma_f32_16x16x32_bf16(ah1, bfr[1][3], a1, 0, 0, 0);
            a2 = __builtin_amdgcn_mfma_f32_16x16x32_bf16(ah1, bfr[2][3], a2, 0, 0, 0);
            a3 = __builtin_amdgcn_mfma_f32_16x16x32_bf16(ah1, bfr[3][3], a3, 0, 0, 0);

            // ---- cell update: sample 0 -> lanes 0-15 reg0, sample 1 -> lanes 16-31 reg0
            if (ln < 32) {
                const float gi = a0[0];
                const float gf = a1[0];
                const float gg = a2[0];
                const float go = a3[0];
                const float iv = 1.f / (1.f + __expf(-gi));
                const float fv = 1.f / (1.f + __expf(-gf));
                const float gv = 1.f - 2.f / (__expf(2.f * gg) + 1.f);   // tanh
                const float ov = 1.f / (1.f + __expf(-go));
                c_st = fv * c_st + iv * gv;
                const float th = 1.f - 2.f / (__expf(2.f * c_st) + 1.f); // tanh
                const float h  = ov * th;
                outp[(size_t)t * (BATCH * HD)] = h;
                hb[p ^ 1][sloc][unit] = f2bf(h);
            }
            p ^= 1;
            __syncthreads();   // h(t) visible for t+1; chunk reads done before refill
        }
    }
}

extern "C" void kernel_launch(void* const* d_in, const int* in_sizes, int n_in,
                              void* d_out, int out_size, void* d_ws, size_t ws_size,
                              hipStream_t stream) {
    const float* x    = (const float*)d_in[0];
    const float* W_ih = (const float*)d_in[1];
    const float* W_hh = (const float*)d_in[2];
    const float* b_ih = (const float*)d_in[3];
    const float* b_hh = (const float*)d_in[4];
    float* out = (float*)d_out;

    lstm_v3<<<BATCH / NS, 256, 0, stream>>>(x, W_ih, W_hh, b_ih, b_hh, out);
}

// Round 6
// 309.896 us; speedup vs baseline: 1.8486x; 1.0367x over previous
//
#include <hip/hip_runtime.h>
#include <hip/hip_bf16.h>

#define SEQ   512
#define BATCH 1024
#define HD    64
#define NS    2      // samples per block -> 512 blocks (2 blocks/CU)
#define TCH   64     // chunk length: x staged in + h-out staged out per chunk

typedef __attribute__((ext_vector_type(8))) short bf16x8;   // 8 bf16 = 4 VGPR
typedef __attribute__((ext_vector_type(4))) float f32x4;    // MFMA acc

// float -> bf16 raw bits, round-to-nearest-even
__device__ __forceinline__ unsigned short f2bf(float f) {
    unsigned u = __float_as_uint(f);
    return (unsigned short)((u + 0x7FFFu + ((u >> 16) & 1u)) >> 16);
}

// Persistent LSTM, 2 samples/block, 512 blocks (2/CU).
// Wave w owns hidden units [16w,16w+16); N-tiles {w,4+w,8+w,12+w} = i/f/g/o.
// Samples at A-rows {0,4} -> D puts sample 0 on lanes 0-15 reg0, sample 1 on
// lanes 16-31 reg0: cell update has NO cross-lane ops. Bias rides the MFMA C
// operand. KEY CHANGE vs v3: no global memory ops inside the per-step barrier
// region -- h outputs stage in LDS (fp32) and dump once per 64-step chunk, so
// the per-step __syncthreads drains only LDS (vmcnt already 0), not a global
// store ack every step.
__global__ __launch_bounds__(256, 2)
void lstm_v4(const float* __restrict__ x,
             const float* __restrict__ W_ih,
             const float* __restrict__ W_hh,
             const float* __restrict__ b_ih,
             const float* __restrict__ b_hh,
             float* __restrict__ out)
{
    __shared__ __align__(16) unsigned short xch[TCH][NS][HD]; // 16 KB bf16 x-chunk
    __shared__ __align__(16) float          ost[TCH][NS][HD]; // 32 KB fp32 h-out staging
    __shared__ __align__(16) unsigned short hb[2][NS][HD];    // 512 B ping-pong h

    const int tid = threadIdx.x;
    const int w   = tid >> 6;        // wave 0..3
    const int ln  = tid & 63;
    const int col = ln & 15;         // MFMA column / unit within wave
    const int kg  = ln >> 4;         // k-group of A/B fragments
    const int sBase = blockIdx.x * NS;

    // ---- one-time: B fragments global fp32 -> bf16 registers ----
    bf16x8 bfr[4][4];                // [gate][k-tile]
    #pragma unroll
    for (int g4 = 0; g4 < 4; ++g4) {
        #pragma unroll
        for (int kt = 0; kt < 4; ++kt) {
            const int n = (g4 * 4 + w) * 16 + col;
            const int k = kt * 32 + kg * 8;
            const float* src = (k < 64) ? (W_ih + n * 64 + k)
                                        : (W_hh + n * 64 + (k - 64));
            const float4 lo = *(const float4*)src;
            const float4 hi = *(const float4*)(src + 4);
            bf16x8 v;
            v[0] = (short)f2bf(lo.x); v[1] = (short)f2bf(lo.y);
            v[2] = (short)f2bf(lo.z); v[3] = (short)f2bf(lo.w);
            v[4] = (short)f2bf(hi.x); v[5] = (short)f2bf(hi.y);
            v[6] = (short)f2bf(hi.z); v[7] = (short)f2bf(hi.w);
            bfr[g4][kt] = v;
        }
    }
    f32x4 bias4[4];                  // C-operand bias (same for all rows)
    #pragma unroll
    for (int g4 = 0; g4 < 4; ++g4) {
        const int gg = g4 * 64 + w * 16 + col;
        const float b = b_ih[gg] + b_hh[gg];
        bias4[g4][0] = b; bias4[g4][1] = b; bias4[g4][2] = b; bias4[g4][3] = b;
    }

    ((unsigned short*)hb)[tid] = 0;  // h0 = 0 (both ping-pong buffers)

    const int row2 = (ln >> 2) & 1;  // A-row parity -> sample slot
    const int sloc = ln >> 4;        // cell lane -> sample (valid for ln<32)
    const int unit = w * 16 + col;

    float c_st = 0.f;
    int p = 0;

    for (int t0 = 0; t0 < SEQ; t0 += TCH) {
        // ======== inter-chunk region: dump prev h-out, refill x. ========
        // (all global traffic lives here; one vmcnt drain per 64 steps)
        if (t0 > 0) {
            const int tp = t0 - TCH;
            #pragma unroll
            for (int j = 0; j < (TCH * NS * HD) / (4 * 256); ++j) {   // 8 iters
                const int idx = tid + j * 256;         // f32x4 index
                const int tt  = idx >> 5;              // 32 f32x4 per step-row
                const int rem = idx & 31;
                const int sl  = rem >> 4, k4 = rem & 15;
                const f32x4 v = *(const f32x4*)&ost[tt][sl][k4 * 4];
                *(f32x4*)&out[(((size_t)(tp + tt) * BATCH) + sBase + sl) * HD + k4 * 4] = v;
            }
        }
        #pragma unroll
        for (int j = 0; j < (TCH * NS * HD) / (2 * 256); ++j) {       // 16 iters
            const int idx = tid + j * 256;
            const int tt = idx >> 6, rem = idx & 63;
            const int sl = rem >> 5, k2 = rem & 31;
            const float2 v = *(const float2*)&x[(((size_t)(t0 + tt) * BATCH) + sBase + sl) * HD + k2 * 2];
            const unsigned pk = (unsigned)f2bf(v.x) | ((unsigned)f2bf(v.y) << 16);
            *(unsigned*)&xch[tt][sl][k2 * 2] = pk;
        }
        __syncthreads();

        // ======== 64 steps, LDS-only barrier regions ========
        for (int tc = 0; tc < TCH; ++tc) {
            const bf16x8 ax0 = *(const bf16x8*)&xch[tc][row2][kg * 8];
            const bf16x8 ax1 = *(const bf16x8*)&xch[tc][row2][32 + kg * 8];
            const bf16x8 ah0 = *(const bf16x8*)&hb[p][row2][kg * 8];
            const bf16x8 ah1 = *(const bf16x8*)&hb[p][row2][32 + kg * 8];

            // x-part first (independent of h), 4 parallel chains
            f32x4 a0 = __builtin_amdgcn_mfma_f32_16x16x32_bf16(ax0, bfr[0][0], bias4[0], 0, 0, 0);
            f32x4 a1 = __builtin_amdgcn_mfma_f32_16x16x32_bf16(ax0, bfr[1][0], bias4[1], 0, 0, 0);
            f32x4 a2 = __builtin_amdgcn_mfma_f32_16x16x32_bf16(ax0, bfr[2][0], bias4[2], 0, 0, 0);
            f32x4 a3 = __builtin_amdgcn_mfma_f32_16x16x32_bf16(ax0, bfr[3][0], bias4[3], 0, 0, 0);
            a0 = __builtin_amdgcn_mfma_f32_16x16x32_bf16(ax1, bfr[0][1], a0, 0, 0, 0);
            a1 = __builtin_amdgcn_mfma_f32_16x16x32_bf16(ax1, bfr[1][1], a1, 0, 0, 0);
            a2 = __builtin_amdgcn_mfma_f32_16x16x32_bf16(ax1, bfr[2][1], a2, 0, 0, 0);
            a3 = __builtin_amdgcn_mfma_f32_16x16x32_bf16(ax1, bfr[3][1], a3, 0, 0, 0);
            a0 = __builtin_amdgcn_mfma_f32_16x16x32_bf16(ah0, bfr[0][2], a0, 0, 0, 0);
            a1 = __builtin_amdgcn_mfma_f32_16x16x32_bf16(ah0, bfr[1][2], a1, 0, 0, 0);
            a2 = __builtin_amdgcn_mfma_f32_16x16x32_bf16(ah0, bfr[2][2], a2, 0, 0, 0);
            a3 = __builtin_amdgcn_mfma_f32_16x16x32_bf16(ah0, bfr[3][2], a3, 0, 0, 0);
            a0 = __builtin_amdgcn_mfma_f32_16x16x32_bf16(ah1, bfr[0][3], a0, 0, 0, 0);
            a1 = __builtin_amdgcn_mfma_f32_16x16x32_bf16(ah1, bfr[1][3], a1, 0, 0, 0);
            a2 = __builtin_amdgcn_mfma_f32_16x16x32_bf16(ah1, bfr[2][3], a2, 0, 0, 0);
            a3 = __builtin_amdgcn_mfma_f32_16x16x32_bf16(ah1, bfr[3][3], a3, 0, 0, 0);

            // cell update: sample 0 -> lanes 0-15 reg0, sample 1 -> lanes 16-31 reg0
            if (ln < 32) {
                const float iv = 1.f / (1.f + __expf(-a0[0]));
                const float fv = 1.f / (1.f + __expf(-a1[0]));
                const float gv = 1.f - 2.f / (__expf(2.f * a2[0]) + 1.f);   // tanh
                const float ov = 1.f / (1.f + __expf(-a3[0]));
                c_st = fv * c_st + iv * gv;
                const float th = 1.f - 2.f / (__expf(2.f * c_st) + 1.f);    // tanh
                const float h  = ov * th;
                ost[tc][sloc][unit] = h;              // LDS staging (no global!)
                hb[p ^ 1][sloc][unit] = f2bf(h);
            }
            p ^= 1;
            __syncthreads();   // LDS-only drain: h(t) visible for t+1
        }
    }

    // ---- final chunk dump ----
    {
        const int tp = SEQ - TCH;
        #pragma unroll
        for (int j = 0; j < (TCH * NS * HD) / (4 * 256); ++j) {
            const int idx = tid + j * 256;
            const int tt  = idx >> 5;
            const int rem = idx & 31;
            const int sl  = rem >> 4, k4 = rem & 15;
            const f32x4 v = *(const f32x4*)&ost[tt][sl][k4 * 4];
            *(f32x4*)&out[(((size_t)(tp + tt) * BATCH) + sBase + sl) * HD + k4 * 4] = v;
        }
    }
}

extern "C" void kernel_launch(void* const* d_in, const int* in_sizes, int n_in,
                              void* d_out, int out_size, void* d_ws, size_t ws_size,
                              hipStream_t stream) {
    const float* x    = (const float*)d_in[0];
    const float* W_ih = (const float*)d_in[1];
    const float* W_hh = (const float*)d_in[2];
    const float* b_ih = (const float*)d_in[3];
    const float* b_hh = (const float*)d_in[4];
    float* out = (float*)d_out;

    lstm_v4<<<BATCH / NS, 256, 0, stream>>>(x, W_ih, W_hh, b_ih, b_hh, out);
}

// Round 7
// 231.044 us; speedup vs baseline: 2.4795x; 1.3413x over previous
//
#include <hip/hip_runtime.h>
#include <hip/hip_bf16.h>

#define SEQ   512
#define BATCH 1024
#define HD    64
#define NS    2      // samples per block -> 512 blocks (2 blocks/CU)
#define TCH   64     // x-chunk steps staged in LDS (16 KB)

typedef __attribute__((ext_vector_type(8))) short bf16x8;   // 8 bf16 = 4 VGPR
typedef __attribute__((ext_vector_type(4))) float f32x4;    // MFMA acc

// float -> bf16 raw bits, round-to-nearest-even
__device__ __forceinline__ unsigned short f2bf(float f) {
    unsigned u = __float_as_uint(f);
    return (unsigned short)((u + 0x7FFFu + ((u >> 16) & 1u)) >> 16);
}
// raw v_rcp_f32 (~1 ulp) -- avoids IEEE div expansion (div_scale/fmas/fixup,
// ~10-instr serial chain each) which dominated the per-step critical path.
__device__ __forceinline__ float frcp(float x) { return __builtin_amdgcn_rcpf(x); }
__device__ __forceinline__ float fsig(float x) { return frcp(1.f + __expf(-x)); }
__device__ __forceinline__ float ftanh(float x) { return 1.f - 2.f * frcp(__expf(2.f * x) + 1.f); }

// Persistent LSTM, 2 samples/block, 512 blocks (2/CU).
// Wave w owns hidden units [16w,16w+16); N-tiles {w,4+w,8+w,12+w} = i/f/g/o.
// Samples at A-rows {0,4} -> D puts sample 0 on lanes 0-15 reg0, sample 1 on
// lanes 16-31 reg0: cell update has NO cross-lane ops. Bias rides the MFMA C
// operand. v7: rcp-based sigmoid/tanh (kills IEEE-div chains), x-part and
// h-part MFMAs as two parallel 2-deep chains merged by scalar adds, next-step
// x-fragments prefetched under the cell.
__global__ __launch_bounds__(256, 2)
void lstm_v5(const float* __restrict__ x,
             const float* __restrict__ W_ih,
             const float* __restrict__ W_hh,
             const float* __restrict__ b_ih,
             const float* __restrict__ b_hh,
             float* __restrict__ out)
{
    __shared__ __align__(16) unsigned short xch[TCH][NS][HD]; // 16 KB bf16
    __shared__ __align__(16) unsigned short hb[2][NS][HD];    // 512 B ping-pong

    const int tid = threadIdx.x;
    const int w   = tid >> 6;        // wave 0..3
    const int ln  = tid & 63;
    const int col = ln & 15;         // MFMA column / unit within wave
    const int kg  = ln >> 4;         // k-group of A/B fragments
    const int sBase = blockIdx.x * NS;

    // ---- one-time: B fragments global fp32 -> bf16 registers ----
    bf16x8 bfr[4][4];                // [gate][k-tile]
    #pragma unroll
    for (int g4 = 0; g4 < 4; ++g4) {
        #pragma unroll
        for (int kt = 0; kt < 4; ++kt) {
            const int n = (g4 * 4 + w) * 16 + col;
            const int k = kt * 32 + kg * 8;
            const float* src = (k < 64) ? (W_ih + n * 64 + k)
                                        : (W_hh + n * 64 + (k - 64));
            const float4 lo = *(const float4*)src;
            const float4 hi = *(const float4*)(src + 4);
            bf16x8 v;
            v[0] = (short)f2bf(lo.x); v[1] = (short)f2bf(lo.y);
            v[2] = (short)f2bf(lo.z); v[3] = (short)f2bf(lo.w);
            v[4] = (short)f2bf(hi.x); v[5] = (short)f2bf(hi.y);
            v[6] = (short)f2bf(hi.z); v[7] = (short)f2bf(hi.w);
            bfr[g4][kt] = v;
        }
    }
    f32x4 bias4[4];                  // C-operand bias (same for all rows)
    #pragma unroll
    for (int g4 = 0; g4 < 4; ++g4) {
        const int gg = g4 * 64 + w * 16 + col;
        const float b = b_ih[gg] + b_hh[gg];
        bias4[g4][0] = b; bias4[g4][1] = b; bias4[g4][2] = b; bias4[g4][3] = b;
    }

    ((unsigned short*)hb)[tid] = 0;  // h0 = 0 (both ping-pong buffers)

    const int row2 = (ln >> 2) & 1;  // A-row parity -> sample slot
    const int sloc = ln >> 4;        // cell lane -> sample (valid for ln<32)
    const int unit = w * 16 + col;

    float c_st = 0.f;
    int p = 0;
    float* outp = out + (size_t)(sBase + sloc) * HD + unit;
    const f32x4 z4 = {0.f, 0.f, 0.f, 0.f};

    for (int t0 = 0; t0 < SEQ; t0 += TCH) {
        // ---- refill x chunk (float2 loads, bf16 pack) ----
        #pragma unroll
        for (int j = 0; j < (TCH * NS * HD) / (256 * 2); ++j) {   // 16 iters
            const int idx = tid + j * 256;
            const int tt = idx >> 6, rem = idx & 63;
            const int sl = rem >> 5, k2 = rem & 31;
            const float2 v = *(const float2*)&x[(((size_t)(t0 + tt) * BATCH) + sBase + sl) * HD + k2 * 2];
            const unsigned pk = (unsigned)f2bf(v.x) | ((unsigned)f2bf(v.y) << 16);
            *(unsigned*)&xch[tt][sl][k2 * 2] = pk;
        }
        __syncthreads();

        bf16x8 ax0 = *(const bf16x8*)&xch[0][row2][kg * 8];
        bf16x8 ax1 = *(const bf16x8*)&xch[0][row2][32 + kg * 8];

        for (int tc = 0; tc < TCH; ++tc) {
            const int t = t0 + tc;
            // h fragments (the only post-barrier latency on the chain)
            const bf16x8 ah0 = *(const bf16x8*)&hb[p][row2][kg * 8];
            const bf16x8 ah1 = *(const bf16x8*)&hb[p][row2][32 + kg * 8];

            // x-part: 4 chains, 2-deep, independent of h
            f32x4 xa0 = __builtin_amdgcn_mfma_f32_16x16x32_bf16(ax0, bfr[0][0], bias4[0], 0, 0, 0);
            f32x4 xa1 = __builtin_amdgcn_mfma_f32_16x16x32_bf16(ax0, bfr[1][0], bias4[1], 0, 0, 0);
            f32x4 xa2 = __builtin_amdgcn_mfma_f32_16x16x32_bf16(ax0, bfr[2][0], bias4[2], 0, 0, 0);
            f32x4 xa3 = __builtin_amdgcn_mfma_f32_16x16x32_bf16(ax0, bfr[3][0], bias4[3], 0, 0, 0);
            xa0 = __builtin_amdgcn_mfma_f32_16x16x32_bf16(ax1, bfr[0][1], xa0, 0, 0, 0);
            xa1 = __builtin_amdgcn_mfma_f32_16x16x32_bf16(ax1, bfr[1][1], xa1, 0, 0, 0);
            xa2 = __builtin_amdgcn_mfma_f32_16x16x32_bf16(ax1, bfr[2][1], xa2, 0, 0, 0);
            xa3 = __builtin_amdgcn_mfma_f32_16x16x32_bf16(ax1, bfr[3][1], xa3, 0, 0, 0);
            // h-part: 4 chains, 2-deep
            f32x4 ha0 = __builtin_amdgcn_mfma_f32_16x16x32_bf16(ah0, bfr[0][2], z4, 0, 0, 0);
            f32x4 ha1 = __builtin_amdgcn_mfma_f32_16x16x32_bf16(ah0, bfr[1][2], z4, 0, 0, 0);
            f32x4 ha2 = __builtin_amdgcn_mfma_f32_16x16x32_bf16(ah0, bfr[2][2], z4, 0, 0, 0);
            f32x4 ha3 = __builtin_amdgcn_mfma_f32_16x16x32_bf16(ah0, bfr[3][2], z4, 0, 0, 0);
            ha0 = __builtin_amdgcn_mfma_f32_16x16x32_bf16(ah1, bfr[0][3], ha0, 0, 0, 0);
            ha1 = __builtin_amdgcn_mfma_f32_16x16x32_bf16(ah1, bfr[1][3], ha1, 0, 0, 0);
            ha2 = __builtin_amdgcn_mfma_f32_16x16x32_bf16(ah1, bfr[2][3], ha2, 0, 0, 0);
            ha3 = __builtin_amdgcn_mfma_f32_16x16x32_bf16(ah1, bfr[3][3], ha3, 0, 0, 0);

            // prefetch next step's x fragments (chunk-stable; hides ds latency)
            bf16x8 nx0 = ax0, nx1 = ax1;
            if (tc + 1 < TCH) {
                nx0 = *(const bf16x8*)&xch[tc + 1][row2][kg * 8];
                nx1 = *(const bf16x8*)&xch[tc + 1][row2][32 + kg * 8];
            }

            // cell update: sample 0 -> lanes 0-15 reg0, sample 1 -> lanes 16-31 reg0
            if (ln < 32) {
                const float gi = xa0[0] + ha0[0];
                const float gf = xa1[0] + ha1[0];
                const float gg = xa2[0] + ha2[0];
                const float go = xa3[0] + ha3[0];
                const float iv = fsig(gi);
                const float fv = fsig(gf);
                const float gv = ftanh(gg);
                const float ov = fsig(go);
                c_st = fv * c_st + iv * gv;
                const float h  = ov * ftanh(c_st);
                outp[(size_t)t * (BATCH * HD)] = h;
                hb[p ^ 1][sloc][unit] = f2bf(h);
            }
            ax0 = nx0; ax1 = nx1;
            p ^= 1;
            __syncthreads();   // h(t) visible for t+1; chunk reads done before refill
        }
    }
}

extern "C" void kernel_launch(void* const* d_in, const int* in_sizes, int n_in,
                              void* d_out, int out_size, void* d_ws, size_t ws_size,
                              hipStream_t stream) {
    const float* x    = (const float*)d_in[0];
    const float* W_ih = (const float*)d_in[1];
    const float* W_hh = (const float*)d_in[2];
    const float* b_ih = (const float*)d_in[3];
    const float* b_hh = (const float*)d_in[4];
    float* out = (float*)d_out;

    lstm_v5<<<BATCH / NS, 256, 0, stream>>>(x, W_ih, W_hh, b_ih, b_hh, out);
}

// Round 9
// 181.179 us; speedup vs baseline: 3.1620x; 1.2752x over previous
//
#include <hip/hip_runtime.h>
#include <hip/hip_bf16.h>

#define SEQ   512
#define BATCH 1024
#define HD    64
#define NS    4      // samples per block -> 256 blocks (1 block/CU, 4 waves)
#define TCH   64     // x-chunk steps staged in LDS
#define XPAD  80     // padded row length (shorts): 160B stride de-conflicts
                     // the 4-slot b128 reads to <=2-way (free, m136)

typedef __attribute__((ext_vector_type(8))) short bf16x8;   // 8 bf16 = 4 VGPR
typedef __attribute__((ext_vector_type(4))) float f32x4;    // MFMA acc

// float -> bf16 raw bits, round-to-nearest-even
__device__ __forceinline__ unsigned short f2bf(float f) {
    unsigned u = __float_as_uint(f);
    return (unsigned short)((u + 0x7FFFu + ((u >> 16) & 1u)) >> 16);
}
// raw v_rcp_f32 (~1 ulp): avoids IEEE div expansion (proven win in v7)
__device__ __forceinline__ float frcp(float x) { return __builtin_amdgcn_rcpf(x); }
__device__ __forceinline__ float fsig(float x) { return frcp(1.f + __expf(-x)); }
__device__ __forceinline__ float ftanh(float x) { return 1.f - 2.f * frcp(__expf(2.f * x) + 1.f); }

// Persistent LSTM, 4 samples/block, 256 blocks (1/CU).
// Wave w owns hidden units [16w,16w+16); N-tiles {w,4+w,8+w,12+w} = i/f/g/o.
// Samples sit at A-rows {0,4,8,12} (slot = row>>2 = (ln>>2)&3), so D-rows
// 4q all land on reg 0: cell update runs on ALL 64 lanes (sample q=ln>>4,
// unit w*16+(ln&15)) with no cross-lane ops. Per-CU per-step MFMA/VALU issue
// is halved vs NS=2x2blocks for the same 4 samples/CU.
__global__ __launch_bounds__(256, 1)
void lstm_v6(const float* __restrict__ x,
             const float* __restrict__ W_ih,
             const float* __restrict__ W_hh,
             const float* __restrict__ b_ih,
             const float* __restrict__ b_hh,
             float* __restrict__ out)
{
    __shared__ __align__(16) unsigned short xch[TCH][NS][XPAD]; // 40 KB bf16
    __shared__ __align__(16) unsigned short hb[2][NS][XPAD];    // 1.25 KB ping-pong

    const int tid  = threadIdx.x;
    const int w    = tid >> 6;        // wave 0..3
    const int ln   = tid & 63;
    const int col  = ln & 15;         // MFMA column / unit within wave
    const int kg   = ln >> 4;         // k-group of A/B fragments
    const int slot = (ln >> 2) & 3;   // A-row (ln&15) -> sample slot (row>>2)
    const int q    = ln >> 4;         // cell-phase sample index
    const int unit = w * 16 + col;
    const int sBase = blockIdx.x * NS;

    // ---- one-time: B fragments global fp32 -> bf16 registers ----
    bf16x8 bfr[4][4];                 // [gate][k-tile]
    #pragma unroll
    for (int g4 = 0; g4 < 4; ++g4) {
        #pragma unroll
        for (int kt = 0; kt < 4; ++kt) {
            const int n = (g4 * 4 + w) * 16 + col;
            const int k = kt * 32 + kg * 8;
            const float* src = (k < 64) ? (W_ih + n * 64 + k)
                                        : (W_hh + n * 64 + (k - 64));
            const float4 lo = *(const float4*)src;
            const float4 hi = *(const float4*)(src + 4);
            bf16x8 v;
            v[0] = (short)f2bf(lo.x); v[1] = (short)f2bf(lo.y);
            v[2] = (short)f2bf(lo.z); v[3] = (short)f2bf(lo.w);
            v[4] = (short)f2bf(hi.x); v[5] = (short)f2bf(hi.y);
            v[6] = (short)f2bf(hi.z); v[7] = (short)f2bf(hi.w);
            bfr[g4][kt] = v;
        }
    }
    // per-lane scalar biases (added on reg0 only, in the cell)
    float bs[4];
    #pragma unroll
    for (int g4 = 0; g4 < 4; ++g4)
        bs[g4] = b_ih[g4 * 64 + unit] + b_hh[g4 * 64 + unit];

    // zero both h buffers (2*NS*XPAD shorts = 320 uints)
    for (int i = tid; i < (2 * NS * XPAD) / 2; i += 256) ((unsigned*)hb)[i] = 0;

    float c_st = 0.f;
    int p = 0;
    float* outp = out + (size_t)(sBase + q) * HD + unit;
    const f32x4 z4 = {0.f, 0.f, 0.f, 0.f};

    for (int t0 = 0; t0 < SEQ; t0 += TCH) {
        // ---- refill x chunk: float4 loads, bf16 pack (16 iters/thread) ----
        #pragma unroll
        for (int j = 0; j < (TCH * NS * 16) / 256; ++j) {
            const int idx = tid + j * 256;      // float4 index
            const int k4 = idx & 15, sl = (idx >> 4) & 3, tt = idx >> 6;
            const float4 v = *(const float4*)&x[(((size_t)(t0 + tt) * BATCH) + sBase + sl) * HD + k4 * 4];
            uint2 pk;
            pk.x = (unsigned)f2bf(v.x) | ((unsigned)f2bf(v.y) << 16);
            pk.y = (unsigned)f2bf(v.z) | ((unsigned)f2bf(v.w) << 16);
            *(uint2*)&xch[tt][sl][k4 * 4] = pk;
        }
        __syncthreads();

        bf16x8 ax0 = *(const bf16x8*)&xch[0][slot][kg * 8];
        bf16x8 ax1 = *(const bf16x8*)&xch[0][slot][32 + kg * 8];

        for (int tc = 0; tc < TCH; ++tc) {
            const int t = t0 + tc;
            // h fragments (the only post-barrier latency on the chain)
            const bf16x8 ah0 = *(const bf16x8*)&hb[p][slot][kg * 8];
            const bf16x8 ah1 = *(const bf16x8*)&hb[p][slot][32 + kg * 8];

            // x-part: 4 chains, 2-deep, independent of h
            f32x4 xa0 = __builtin_amdgcn_mfma_f32_16x16x32_bf16(ax0, bfr[0][0], z4, 0, 0, 0);
            f32x4 xa1 = __builtin_amdgcn_mfma_f32_16x16x32_bf16(ax0, bfr[1][0], z4, 0, 0, 0);
            f32x4 xa2 = __builtin_amdgcn_mfma_f32_16x16x32_bf16(ax0, bfr[2][0], z4, 0, 0, 0);
            f32x4 xa3 = __builtin_amdgcn_mfma_f32_16x16x32_bf16(ax0, bfr[3][0], z4, 0, 0, 0);
            xa0 = __builtin_amdgcn_mfma_f32_16x16x32_bf16(ax1, bfr[0][1], xa0, 0, 0, 0);
            xa1 = __builtin_amdgcn_mfma_f32_16x16x32_bf16(ax1, bfr[1][1], xa1, 0, 0, 0);
            xa2 = __builtin_amdgcn_mfma_f32_16x16x32_bf16(ax1, bfr[2][1], xa2, 0, 0, 0);
            xa3 = __builtin_amdgcn_mfma_f32_16x16x32_bf16(ax1, bfr[3][1], xa3, 0, 0, 0);
            // h-part: 4 chains, 2-deep
            f32x4 ha0 = __builtin_amdgcn_mfma_f32_16x16x32_bf16(ah0, bfr[0][2], z4, 0, 0, 0);
            f32x4 ha1 = __builtin_amdgcn_mfma_f32_16x16x32_bf16(ah0, bfr[1][2], z4, 0, 0, 0);
            f32x4 ha2 = __builtin_amdgcn_mfma_f32_16x16x32_bf16(ah0, bfr[2][2], z4, 0, 0, 0);
            f32x4 ha3 = __builtin_amdgcn_mfma_f32_16x16x32_bf16(ah0, bfr[3][2], z4, 0, 0, 0);
            ha0 = __builtin_amdgcn_mfma_f32_16x16x32_bf16(ah1, bfr[0][3], ha0, 0, 0, 0);
            ha1 = __builtin_amdgcn_mfma_f32_16x16x32_bf16(ah1, bfr[1][3], ha1, 0, 0, 0);
            ha2 = __builtin_amdgcn_mfma_f32_16x16x32_bf16(ah1, bfr[2][3], ha2, 0, 0, 0);
            ha3 = __builtin_amdgcn_mfma_f32_16x16x32_bf16(ah1, bfr[3][3], ha3, 0, 0, 0);

            // prefetch next step's x fragments (chunk-stable; hides ds latency)
            bf16x8 nx0 = ax0, nx1 = ax1;
            if (tc + 1 < TCH) {
                nx0 = *(const bf16x8*)&xch[tc + 1][slot][kg * 8];
                nx1 = *(const bf16x8*)&xch[tc + 1][slot][32 + kg * 8];
            }

            // ---- cell update on ALL 64 lanes: sample q, unit w*16+col ----
            const float gi = xa0[0] + ha0[0] + bs[0];
            const float gf = xa1[0] + ha1[0] + bs[1];
            const float gg = xa2[0] + ha2[0] + bs[2];
            const float go = xa3[0] + ha3[0] + bs[3];
            const float iv = fsig(gi);
            const float fv = fsig(gf);
            const float gv = ftanh(gg);
            const float ov = fsig(go);
            c_st = fv * c_st + iv * gv;
            const float h  = ov * ftanh(c_st);
            outp[(size_t)t * (BATCH * HD)] = h;
            hb[p ^ 1][q][unit] = f2bf(h);

            ax0 = nx0; ax1 = nx1;
            p ^= 1;
            __syncthreads();   // h(t) visible for t+1; chunk reads done pre-refill
        }
    }
}

extern "C" void kernel_launch(void* const* d_in, const int* in_sizes, int n_in,
                              void* d_out, int out_size, void* d_ws, size_t ws_size,
                              hipStream_t stream) {
    const float* x    = (const float*)d_in[0];
    const float* W_ih = (const float*)d_in[1];
    const float* W_hh = (const float*)d_in[2];
    const float* b_ih = (const float*)d_in[3];
    const float* b_hh = (const float*)d_in[4];
    float* out = (float*)d_out;

    lstm_v6<<<BATCH / NS, 256, 0, stream>>>(x, W_ih, W_hh, b_ih, b_hh, out);
}